// Round 11
// baseline (440.432 us; speedup 1.0000x reference)
//
#include <hip/hip_runtime.h>

#define D_MODEL 1024
#define NHEADS  16
#define DK      64
#define SEQ     2048
#define NBATCH  2
#define MTOT    (NBATCH * SEQ)   // 4096 rows

typedef _Float16 f16;
typedef _Float16 f16x4 __attribute__((ext_vector_type(4)));
typedef _Float16 f16x8 __attribute__((ext_vector_type(8)));
typedef float    f32x4 __attribute__((ext_vector_type(4)));
typedef float    f32x16 __attribute__((ext_vector_type(16)));

#define LOG2E 1.44269504088896340736f

// ---------------------------------------------------------------------------
// fp32 -> fp16 convert (inputs + weights), one batched launch.
// [separate cvt + DMA staging beats fused-A-cvt: R8/R9 counter evidence]
// ---------------------------------------------------------------------------
__global__ __launch_bounds__(256) void cvt_f32_to_f16(
    const float* __restrict__ q, const float* __restrict__ k, const float* __restrict__ v,
    const float* __restrict__ wq, const float* __restrict__ wk,
    const float* __restrict__ wv, const float* __restrict__ wo,
    f16* __restrict__ qf, f16* __restrict__ kf, f16* __restrict__ vf,
    f16* __restrict__ wqh, f16* __restrict__ wkh, f16* __restrict__ wvh, f16* __restrict__ woh)
{
    const int z = blockIdx.y;
    const float* src; f16* dst; int n4;
    if (z == 0)      { src = q;  dst = qf;  n4 = MTOT * D_MODEL / 4; }
    else if (z == 1) { src = k;  dst = kf;  n4 = MTOT * D_MODEL / 4; }
    else if (z == 2) { src = v;  dst = vf;  n4 = MTOT * D_MODEL / 4; }
    else if (z == 3) { src = wq; dst = wqh; n4 = D_MODEL * D_MODEL / 4; }
    else if (z == 4) { src = wk; dst = wkh; n4 = D_MODEL * D_MODEL / 4; }
    else if (z == 5) { src = wv; dst = wvh; n4 = D_MODEL * D_MODEL / 4; }
    else             { src = wo; dst = woh; n4 = D_MODEL * D_MODEL / 4; }
    for (int i = blockIdx.x * 256 + threadIdx.x; i < n4; i += gridDim.x * 256) {
        float4 t = ((const float4*)src)[i];
        f16x4 o = {(f16)t.x, (f16)t.y, (f16)t.z, (f16)t.w};
        ((f16x4*)dst)[i] = o;
    }
}

// ---------------------------------------------------------------------------
// f16 GEMM core: BK=32 DMA staging (global_load_lds w16, chunk slot=ko*128+m)
// + 32x32x16 MFMA inner. 128x128 tile, 4 waves (2x2), wave 64x64 = 2x2 tiles.
// C/D: col=lane&31, row=(r&3)+8*(r>>2)+4*(lane>>5)  [m74/m101 verified].
// ---------------------------------------------------------------------------
__device__ __forceinline__ void gemm128_core(
    const f16* __restrict__ A, const f16* __restrict__ Wm,
    int m0, int n0, int kbeg, int kend, f32x16 (&acc)[2][2])
{
    __shared__ __align__(16) f16 As[4096];
    __shared__ __align__(16) f16 Bs[4096];

    const int t    = threadIdx.x;
    const int lane = t & 63;
    const int w    = t >> 6;
    const int l31  = lane & 31, kg = lane >> 5;
    const int wr   = w >> 1,    wc = w & 1;

    size_t offA[2], offB[2];
#pragma unroll
    for (int jj = 0; jj < 2; ++jj) {
        int s  = (w * 2 + jj) * 64 + lane;
        int ko = s >> 7, m = s & 127;
        offA[jj] = (size_t)(m0 + m) * D_MODEL + ko * 8;
        offB[jj] = (size_t)(n0 + m) * D_MODEL + ko * 8;
    }
    const int jb = __builtin_amdgcn_readfirstlane(w * 1024);

#pragma unroll
    for (int i = 0; i < 2; ++i)
#pragma unroll
        for (int j = 0; j < 2; ++j)
#pragma unroll
            for (int r = 0; r < 16; ++r) acc[i][j][r] = 0.f;

    auto* ldsA = (__attribute__((address_space(3))) f16*)As;
    auto* ldsB = (__attribute__((address_space(3))) f16*)Bs;

    for (int k0 = kbeg; k0 < kend; k0 += 32) {
#pragma unroll
        for (int jj = 0; jj < 2; ++jj) {
            __builtin_amdgcn_global_load_lds(
                (const __attribute__((address_space(1))) void*)(A + offA[jj] + k0),
                (__attribute__((address_space(3))) void*)(ldsA + jb + jj * 512),
                16, 0, 0);
            __builtin_amdgcn_global_load_lds(
                (const __attribute__((address_space(1))) void*)(Wm + offB[jj] + k0),
                (__attribute__((address_space(3))) void*)(ldsB + jb + jj * 512),
                16, 0, 0);
        }
        __syncthreads();

#pragma unroll
        for (int step = 0; step < 2; ++step) {
            const int kk = kg + 2 * step;
            f16x8 aF[2], bF[2];
#pragma unroll
            for (int ti = 0; ti < 2; ++ti) {
                aF[ti] = *(const f16x8*)&As[(kk * 128 + wr * 64 + ti * 32 + l31) * 8];
                bF[ti] = *(const f16x8*)&Bs[(kk * 128 + wc * 64 + ti * 32 + l31) * 8];
            }
#pragma unroll
            for (int ti = 0; ti < 2; ++ti)
#pragma unroll
                for (int tj = 0; tj < 2; ++tj)
                    acc[ti][tj] = __builtin_amdgcn_mfma_f32_32x32x16_f16(
                        aF[ti], bF[tj], acc[ti][tj], 0, 0, 0);
        }
        __syncthreads();
    }
}

// ---------------------------------------------------------------------------
// Fused Q/K/V projection (f16 in/out), XCD-swizzled grid (x=mtile 32,
// y=ntile 8, z=3): id%8 = mtile%8 -> the 8 n-blocks sharing an A-tile
// co-locate on one XCD. Q output pre-scaled by 0.125*log2(e).
// ---------------------------------------------------------------------------
__global__ __launch_bounds__(256, 3) void qkv_gemm(
    const f16* __restrict__ Qf, const f16* __restrict__ Kf, const f16* __restrict__ Vf,
    const f16* __restrict__ Wqh, const f16* __restrict__ Wkh, const f16* __restrict__ Wvh,
    const float* __restrict__ bq, const float* __restrict__ bk, const float* __restrict__ bv,
    f16* __restrict__ Qh, f16* __restrict__ Kh, f16* __restrict__ Vt)
{
    const int z = blockIdx.z;
    const f16*   A    = z == 0 ? Qf  : z == 1 ? Kf  : Vf;
    const f16*   Wm   = z == 0 ? Wqh : z == 1 ? Wkh : Wvh;
    const float* bias = z == 0 ? bq  : z == 1 ? bk  : bv;

    const int m0 = blockIdx.x * 128, n0 = blockIdx.y * 128;   // XCD swizzle
    f32x16 acc[2][2];
    gemm128_core(A, Wm, m0, n0, 0, D_MODEL, acc);

    const int t = threadIdx.x, lane = t & 63, w = t >> 6;
    const int l31 = lane & 31, kg = lane >> 5;
    const int wr = w >> 1, wc = w & 1;

    if (z < 2) {
        f16* Out = z == 0 ? Qh : Kh;
        const float sc = z == 0 ? 0.125f * LOG2E : 1.0f;
#pragma unroll
        for (int tj = 0; tj < 2; ++tj) {
            const int col = n0 + wc * 64 + tj * 32 + l31;
            const float bc = bias[col];
#pragma unroll
            for (int ti = 0; ti < 2; ++ti)
#pragma unroll
                for (int r = 0; r < 16; ++r) {
                    const int row = m0 + wr * 64 + ti * 32 + (r & 3) + 8 * (r >> 2) + 4 * kg;
                    Out[(size_t)row * D_MODEL + col] = (f16)((acc[ti][tj][r] + bc) * sc);
                }
        }
    } else {
        // V transposed: Vt[(b*16+h)*64 + d][s]
#pragma unroll
        for (int tj = 0; tj < 2; ++tj) {
            const int col = n0 + wc * 64 + tj * 32 + l31;
            const float bc = bias[col];
            const int h = col >> 6, d = col & 63;
#pragma unroll
            for (int ti = 0; ti < 2; ++ti)
#pragma unroll
                for (int r = 0; r < 16; ++r) {
                    const int row = m0 + wr * 64 + ti * 32 + (r & 3) + 8 * (r >> 2) + 4 * kg;
                    const int bb = row >> 11, s = row & (SEQ - 1);
                    Vt[(size_t)((bb * NHEADS + h) * DK + d) * SEQ + s] = (f16)(acc[ti][tj][r] + bc);
                }
        }
    }
}

// Output projection, split-K=2, XCD-swizzled grid (x=mtile 32, y=ntile 8, z).
__global__ __launch_bounds__(256, 3) void oproj_splitk(
    const f16* __restrict__ A, const f16* __restrict__ Wm,
    float* __restrict__ P0, float* __restrict__ P1)
{
    const int z = blockIdx.z;
    const int m0 = blockIdx.x * 128, n0 = blockIdx.y * 128;   // XCD swizzle
    f32x16 acc[2][2];
    gemm128_core(A, Wm, m0, n0, z * 512, z * 512 + 512, acc);

    float* Out = z == 0 ? P0 : P1;
    const int t = threadIdx.x, lane = t & 63, w = t >> 6;
    const int l31 = lane & 31, kg = lane >> 5;
    const int wr = w >> 1, wc = w & 1;
#pragma unroll
    for (int tj = 0; tj < 2; ++tj) {
        const int col = n0 + wc * 64 + tj * 32 + l31;
#pragma unroll
        for (int ti = 0; ti < 2; ++ti)
#pragma unroll
            for (int r = 0; r < 16; ++r) {
                const int row = m0 + wr * 64 + ti * 32 + (r & 3) + 8 * (r >> 2) + 4 * kg;
                Out[(size_t)row * D_MODEL + col] = acc[ti][tj][r];
            }
    }
}

// Reduce partials + bias -> final fp32 output.
__global__ __launch_bounds__(256) void reduce_bias(
    const float* __restrict__ P0, const float* __restrict__ P1,
    const float* __restrict__ bias, float* __restrict__ Out)
{
    const int n4 = MTOT * D_MODEL / 4;
    for (int i = blockIdx.x * 256 + threadIdx.x; i < n4; i += gridDim.x * 256) {
        float4 a = ((const float4*)P0)[i];
        float4 b = ((const float4*)P1)[i];
        float4 c = ((const float4*)bias)[i & 255];
        float4 o = {a.x + b.x + c.x, a.y + b.y + c.y,
                    a.z + b.z + c.z, a.w + b.w + c.w};
        ((float4*)Out)[i] = o;
    }
}

// ---------------------------------------------------------------------------
// Flash attention v8: static exp2 softmax, keys split in THIRDS (tiles
// 0-10 / 11-21 / 22-31), grid (bh=32, qt=16, 3) = 1536 blocks = 6 blocks/CU.
// Ps shrunk to one 16-row region per wave reused across both strips
// (in-order per-wave DS ops make write-after-read safe) -> LDS 24.5 KB,
// 6 x 24.5 = 147 <= 160 KB. id%8 = bh%8 keeps R10's K/V XCD locality.
// Partials: O f16 unnormalized, sacc f32; combine sums 3 linearly.
// ---------------------------------------------------------------------------
__global__ __launch_bounds__(256, 6) void mha_mfma_v8(
    const f16* __restrict__ Qh, const f16* __restrict__ Kh,
    const f16* __restrict__ Vt, f16* __restrict__ Op, float* __restrict__ sp)
{
    __shared__ __align__(16) f16 Ks[4096];
    __shared__ __align__(16) f16 Vc[4096];
    __shared__ __align__(16) f16 Ps[64 * 68];

    const int t    = threadIdx.x;
    const int w    = t >> 6;
    const int lane = t & 63;
    const int quad = lane >> 4, l15 = lane & 15;

    const int bh = blockIdx.x, qt = blockIdx.y, third = blockIdx.z;
    const int b  = bh >> 4,    h  = bh & 15;
    const int q0 = qt * 128;

    f16x8 aQ[2][2];
#pragma unroll
    for (int s = 0; s < 2; ++s)
#pragma unroll
        for (int c = 0; c < 2; ++c)
            aQ[s][c] = *(const f16x8*)&Qh[
                (size_t)(b * SEQ + q0 + w * 32 + s * 16 + l15) * D_MODEL
                + h * DK + c * 32 + quad * 8];

    const f16* gK[2]; const f16* gV[2]; int ldst[2];
#pragma unroll
    for (int jj = 0; jj < 2; ++jj) {
        const int kc = w * 2 + jj;
        gK[jj] = Kh + (size_t)(b * SEQ + lane) * D_MODEL + h * DK + kc * 8;
        gV[jj] = Vt + (size_t)(bh * DK + lane) * SEQ + kc * 8;
        ldst[jj] = __builtin_amdgcn_readfirstlane(kc * 512);
    }
    auto* ldsK = (__attribute__((address_space(3))) f16*)Ks;
    auto* ldsV = (__attribute__((address_space(3))) f16*)Vc;

    const f16x8 onesB = {(f16)1.f, (f16)1.f, (f16)1.f, (f16)1.f,
                         (f16)1.f, (f16)1.f, (f16)1.f, (f16)1.f};

    f32x4 o[2][4];
#pragma unroll
    for (int s = 0; s < 2; ++s)
#pragma unroll
        for (int j = 0; j < 4; ++j) o[s][j] = (f32x4){0.f, 0.f, 0.f, 0.f};
    f32x4 sacc[2] = {(f32x4){0.f, 0.f, 0.f, 0.f}, (f32x4){0.f, 0.f, 0.f, 0.f}};

    const int kt0   = third * 11;                         // 0, 11, 22
    const int ktend = (third == 2) ? 32 : kt0 + 11;       // 11, 22, 32
    for (int kt = kt0; kt < ktend; ++kt) {
#pragma unroll
        for (int jj = 0; jj < 2; ++jj) {
            __builtin_amdgcn_global_load_lds(
                (const __attribute__((address_space(1))) void*)(gK[jj] + (size_t)kt * 64 * D_MODEL),
                (__attribute__((address_space(3))) void*)(ldsK + ldst[jj]), 16, 0, 0);
            __builtin_amdgcn_global_load_lds(
                (const __attribute__((address_space(1))) void*)(gV[jj] + kt * 64),
                (__attribute__((address_space(3))) void*)(ldsV + ldst[jj]), 16, 0, 0);
        }
        __syncthreads();

        f16x8 bK[4][2], bV[4][2];
#pragma unroll
        for (int f = 0; f < 4; ++f)
#pragma unroll
            for (int c = 0; c < 2; ++c) {
                const int slot = ((c * 4 + quad) * 64 + f * 16 + l15) * 8;
                bK[f][c] = *(const f16x8*)&Ks[slot];
                bV[f][c] = *(const f16x8*)&Vc[slot];
            }

#pragma unroll
        for (int s = 0; s < 2; ++s) {
            f32x4 sc[4];
#pragma unroll
            for (int f = 0; f < 4; ++f) {
                f32x4 a = (f32x4){0.f, 0.f, 0.f, 0.f};
                a = __builtin_amdgcn_mfma_f32_16x16x32_f16(aQ[s][0], bK[f][0], a, 0, 0, 0);
                a = __builtin_amdgcn_mfma_f32_16x16x32_f16(aQ[s][1], bK[f][1], a, 0, 0, 0);
                sc[f] = a;
            }

#pragma unroll
            for (int f = 0; f < 4; ++f)
#pragma unroll
                for (int r = 0; r < 4; ++r)
                    sc[f][r] = __builtin_exp2f(sc[f][r]);

            // per-wave 16-row Ps region, reused across s (in-order DS)
#pragma unroll
            for (int f = 0; f < 4; ++f)
#pragma unroll
                for (int r = 0; r < 4; ++r)
                    Ps[(w * 16 + quad * 4 + r) * 68 + f * 16 + l15] = (f16)sc[f][r];

            f16x8 aP[2];
#pragma unroll
            for (int c = 0; c < 2; ++c) {
                const int off = (w * 16 + l15) * 68 + c * 32 + quad * 8;
                f16x4 lo = *(const f16x4*)&Ps[off];
                f16x4 hi = *(const f16x4*)&Ps[off + 4];
                aP[c] = __builtin_shufflevector(lo, hi, 0, 1, 2, 3, 4, 5, 6, 7);
            }

#pragma unroll
            for (int j = 0; j < 4; ++j) {
                o[s][j] = __builtin_amdgcn_mfma_f32_16x16x32_f16(aP[0], bV[j][0], o[s][j], 0, 0, 0);
                o[s][j] = __builtin_amdgcn_mfma_f32_16x16x32_f16(aP[1], bV[j][1], o[s][j], 0, 0, 0);
            }
            sacc[s] = __builtin_amdgcn_mfma_f32_16x16x32_f16(aP[0], onesB, sacc[s], 0, 0, 0);
            sacc[s] = __builtin_amdgcn_mfma_f32_16x16x32_f16(aP[1], onesB, sacc[s], 0, 0, 0);
        }
        __syncthreads();
    }

    // ---- epilogue: unnormalized O partial (f16) + sacc partial (f32) ----
#pragma unroll
    for (int s = 0; s < 2; ++s)
#pragma unroll
        for (int r = 0; r < 4; ++r) {
            const int qrow = q0 + w * 32 + s * 16 + quad * 4 + r;
            const size_t base = ((size_t)(third * 32 + bh) * SEQ + qrow) * DK;
#pragma unroll
            for (int j = 0; j < 4; ++j)
                Op[base + j * 16 + l15] = (f16)o[s][j][r];
            if (l15 == 0)
                sp[(size_t)(third * 32 + bh) * SEQ + qrow] = sacc[s][r];
        }
}

// Combine: O = (O0+O1+O2)/(s0+s1+s2) -> ATh f16 natural [B*S, D_MODEL].
__global__ __launch_bounds__(256) void mha_combine(
    const f16* __restrict__ Op, const float* __restrict__ sp,
    f16* __restrict__ ATh)
{
    const int gid = blockIdx.x * 256 + threadIdx.x;
    const int d4 = gid & 15;
    const int q  = (gid >> 4) & (SEQ - 1);
    const int bh = gid >> 15;
    const int b = bh >> 4, h = bh & 15;

    float acc[4] = {0.f, 0.f, 0.f, 0.f};
    float ssum = 0.f;
#pragma unroll
    for (int tpart = 0; tpart < 3; ++tpart) {
        const size_t idx = ((size_t)(tpart * 32 + bh) * SEQ + q) * DK + d4 * 4;
        f16x4 a = *(const f16x4*)&Op[idx];
#pragma unroll
        for (int m = 0; m < 4; ++m) acc[m] += (float)a[m];
        ssum += sp[(size_t)(tpart * 32 + bh) * SEQ + q];
    }
    const float inv = 1.f / ssum;
    f16x4 r;
#pragma unroll
    for (int m = 0; m < 4; ++m) r[m] = (f16)(acc[m] * inv);
    *(f16x4*)&ATh[((size_t)(b * SEQ + q)) * D_MODEL + h * DK + d4 * 4] = r;
}

// ---------------------------------------------------------------------------
extern "C" void kernel_launch(void* const* d_in, const int* in_sizes, int n_in,
                              void* d_out, int out_size, void* d_ws, size_t ws_size,
                              hipStream_t stream)
{
    const float* query = (const float*)d_in[0];
    const float* key   = (const float*)d_in[1];
    const float* value = (const float*)d_in[2];
    const float* Wq    = (const float*)d_in[3];
    const float* bq    = (const float*)d_in[4];
    const float* Wk    = (const float*)d_in[5];
    const float* bk    = (const float*)d_in[6];
    const float* Wv    = (const float*)d_in[7];
    const float* bv    = (const float*)d_in[8];
    const float* Wo    = (const float*)d_in[9];
    const float* bo    = (const float*)d_in[10];
    float* out = (float*)d_out;

    // ws layout (f16 elems), 64 MB total:
    //   Qf Kf Vf (4M ea) | Wqh Wkh Wvh Woh (1M ea) | Qh Kh Vt ATh (4M ea)
    // Stream-ordered overlays of dead regions:
    //   Op (12M f16 = 24 MB, 3 thirds) over Qf+Kf+Vf (dead after qkv_gemm)
    //   sp (192K f32) over Wqh (dead after qkv_gemm)
    //   P0 (4M f32) over Qf+Kf (Op dead after combine)
    //   P1 (4M f32) over Qh+Kh (dead after combine)
    f16* Qf  = (f16*)d_ws;
    f16* Kf  = Qf  + (size_t)MTOT * D_MODEL;
    f16* Vf  = Kf  + (size_t)MTOT * D_MODEL;
    f16* Wqh = Vf  + (size_t)MTOT * D_MODEL;
    f16* Wkh = Wqh + (size_t)D_MODEL * D_MODEL;
    f16* Wvh = Wkh + (size_t)D_MODEL * D_MODEL;
    f16* Woh = Wvh + (size_t)D_MODEL * D_MODEL;
    f16* Qh  = Woh + (size_t)D_MODEL * D_MODEL;
    f16* Kh  = Qh  + (size_t)MTOT * D_MODEL;
    f16* Vt  = Kh  + (size_t)MTOT * D_MODEL;
    f16* ATh = Vt  + (size_t)MTOT * D_MODEL;

    f16*   Op = Qf;                 // 3*32*2048*64 f16 = 12M f16 = 24 MB
    float* sp = (float*)Wqh;        // 3*32*2048 f32 = 0.75 MB
    float* P0 = (float*)Qf;
    float* P1 = (float*)Qh;

    cvt_f32_to_f16<<<dim3(1024, 7), 256, 0, stream>>>(
        query, key, value, Wq, Wk, Wv, Wo, Qf, Kf, Vf, Wqh, Wkh, Wvh, Woh);

    qkv_gemm<<<dim3(MTOT / 128, D_MODEL / 128, 3), 256, 0, stream>>>(
        Qf, Kf, Vf, Wqh, Wkh, Wvh, bq, bk, bv, Qh, Kh, Vt);

    mha_mfma_v8<<<dim3(NBATCH * NHEADS, SEQ / 128, 3), 256, 0, stream>>>(
        Qh, Kh, Vt, Op, sp);

    mha_combine<<<dim3(MTOT * D_MODEL / 4 / 256), 256, 0, stream>>>(Op, sp, ATh);

    oproj_splitk<<<dim3(MTOT / 128, D_MODEL / 128, 2), 256, 0, stream>>>(ATh, Woh, P0, P1);

    reduce_bias<<<dim3(1024), 256, 0, stream>>>(P0, P1, bo, out);
}

// Round 12
// 263.844 us; speedup vs baseline: 1.6693x; 1.6693x over previous
//
#include <hip/hip_runtime.h>

#define D_MODEL 1024
#define NHEADS  16
#define DK      64
#define SEQ     2048
#define NBATCH  2
#define MTOT    (NBATCH * SEQ)   // 4096 rows

typedef _Float16 f16;
typedef _Float16 f16x4 __attribute__((ext_vector_type(4)));
typedef _Float16 f16x8 __attribute__((ext_vector_type(8)));
typedef float    f32x4 __attribute__((ext_vector_type(4)));
typedef float    f32x16 __attribute__((ext_vector_type(16)));

#define LOG2E 1.44269504088896340736f

// ---------------------------------------------------------------------------
// fp32 -> fp16 convert (inputs + weights), one batched launch.
// ---------------------------------------------------------------------------
__global__ __launch_bounds__(256) void cvt_f32_to_f16(
    const float* __restrict__ q, const float* __restrict__ k, const float* __restrict__ v,
    const float* __restrict__ wq, const float* __restrict__ wk,
    const float* __restrict__ wv, const float* __restrict__ wo,
    f16* __restrict__ qf, f16* __restrict__ kf, f16* __restrict__ vf,
    f16* __restrict__ wqh, f16* __restrict__ wkh, f16* __restrict__ wvh, f16* __restrict__ woh)
{
    const int z = blockIdx.y;
    const float* src; f16* dst; int n4;
    if (z == 0)      { src = q;  dst = qf;  n4 = MTOT * D_MODEL / 4; }
    else if (z == 1) { src = k;  dst = kf;  n4 = MTOT * D_MODEL / 4; }
    else if (z == 2) { src = v;  dst = vf;  n4 = MTOT * D_MODEL / 4; }
    else if (z == 3) { src = wq; dst = wqh; n4 = D_MODEL * D_MODEL / 4; }
    else if (z == 4) { src = wk; dst = wkh; n4 = D_MODEL * D_MODEL / 4; }
    else if (z == 5) { src = wv; dst = wvh; n4 = D_MODEL * D_MODEL / 4; }
    else             { src = wo; dst = woh; n4 = D_MODEL * D_MODEL / 4; }
    for (int i = blockIdx.x * 256 + threadIdx.x; i < n4; i += gridDim.x * 256) {
        float4 t = ((const float4*)src)[i];
        f16x4 o = {(f16)t.x, (f16)t.y, (f16)t.z, (f16)t.w};
        ((f16x4*)dst)[i] = o;
    }
}

// ---------------------------------------------------------------------------
// f16 GEMM core: BK=32 DMA staging (global_load_lds w16, chunk slot=ko*128+m)
// + 32x32x16 MFMA inner. 128x128 tile, 4 waves (2x2), wave 64x64 = 2x2 tiles.
// C/D: col=lane&31, row=(r&3)+8*(r>>2)+4*(lane>>5)  [m74/m101 verified].
// ---------------------------------------------------------------------------
__device__ __forceinline__ void gemm128_core(
    const f16* __restrict__ A, const f16* __restrict__ Wm,
    int m0, int n0, int kbeg, int kend, f32x16 (&acc)[2][2])
{
    __shared__ __align__(16) f16 As[4096];
    __shared__ __align__(16) f16 Bs[4096];

    const int t    = threadIdx.x;
    const int lane = t & 63;
    const int w    = t >> 6;
    const int l31  = lane & 31, kg = lane >> 5;
    const int wr   = w >> 1,    wc = w & 1;

    size_t offA[2], offB[2];
#pragma unroll
    for (int jj = 0; jj < 2; ++jj) {
        int s  = (w * 2 + jj) * 64 + lane;
        int ko = s >> 7, m = s & 127;
        offA[jj] = (size_t)(m0 + m) * D_MODEL + ko * 8;
        offB[jj] = (size_t)(n0 + m) * D_MODEL + ko * 8;
    }
    const int jb = __builtin_amdgcn_readfirstlane(w * 1024);

#pragma unroll
    for (int i = 0; i < 2; ++i)
#pragma unroll
        for (int j = 0; j < 2; ++j)
#pragma unroll
            for (int r = 0; r < 16; ++r) acc[i][j][r] = 0.f;

    auto* ldsA = (__attribute__((address_space(3))) f16*)As;
    auto* ldsB = (__attribute__((address_space(3))) f16*)Bs;

    for (int k0 = kbeg; k0 < kend; k0 += 32) {
#pragma unroll
        for (int jj = 0; jj < 2; ++jj) {
            __builtin_amdgcn_global_load_lds(
                (const __attribute__((address_space(1))) void*)(A + offA[jj] + k0),
                (__attribute__((address_space(3))) void*)(ldsA + jb + jj * 512),
                16, 0, 0);
            __builtin_amdgcn_global_load_lds(
                (const __attribute__((address_space(1))) void*)(Wm + offB[jj] + k0),
                (__attribute__((address_space(3))) void*)(ldsB + jb + jj * 512),
                16, 0, 0);
        }
        __syncthreads();

#pragma unroll
        for (int step = 0; step < 2; ++step) {
            const int kk = kg + 2 * step;
            f16x8 aF[2], bF[2];
#pragma unroll
            for (int ti = 0; ti < 2; ++ti) {
                aF[ti] = *(const f16x8*)&As[(kk * 128 + wr * 64 + ti * 32 + l31) * 8];
                bF[ti] = *(const f16x8*)&Bs[(kk * 128 + wc * 64 + ti * 32 + l31) * 8];
            }
#pragma unroll
            for (int ti = 0; ti < 2; ++ti)
#pragma unroll
                for (int tj = 0; tj < 2; ++tj)
                    acc[ti][tj] = __builtin_amdgcn_mfma_f32_32x32x16_f16(
                        aF[ti], bF[tj], acc[ti][tj], 0, 0, 0);
        }
        __syncthreads();
    }
}

// ---------------------------------------------------------------------------
// Fused Q/K/V projection (f16 in/out), XCD-swizzled grid (x=mtile 32,
// y=ntile 8, z=3). Q output pre-scaled by 0.125*log2(e).
// ---------------------------------------------------------------------------
__global__ __launch_bounds__(256, 3) void qkv_gemm(
    const f16* __restrict__ Qf, const f16* __restrict__ Kf, const f16* __restrict__ Vf,
    const f16* __restrict__ Wqh, const f16* __restrict__ Wkh, const f16* __restrict__ Wvh,
    const float* __restrict__ bq, const float* __restrict__ bk, const float* __restrict__ bv,
    f16* __restrict__ Qh, f16* __restrict__ Kh, f16* __restrict__ Vt)
{
    const int z = blockIdx.z;
    const f16*   A    = z == 0 ? Qf  : z == 1 ? Kf  : Vf;
    const f16*   Wm   = z == 0 ? Wqh : z == 1 ? Wkh : Wvh;
    const float* bias = z == 0 ? bq  : z == 1 ? bk  : bv;

    const int m0 = blockIdx.x * 128, n0 = blockIdx.y * 128;   // XCD swizzle
    f32x16 acc[2][2];
    gemm128_core(A, Wm, m0, n0, 0, D_MODEL, acc);

    const int t = threadIdx.x, lane = t & 63, w = t >> 6;
    const int l31 = lane & 31, kg = lane >> 5;
    const int wr = w >> 1, wc = w & 1;

    if (z < 2) {
        f16* Out = z == 0 ? Qh : Kh;
        const float sc = z == 0 ? 0.125f * LOG2E : 1.0f;
#pragma unroll
        for (int tj = 0; tj < 2; ++tj) {
            const int col = n0 + wc * 64 + tj * 32 + l31;
            const float bc = bias[col];
#pragma unroll
            for (int ti = 0; ti < 2; ++ti)
#pragma unroll
                for (int r = 0; r < 16; ++r) {
                    const int row = m0 + wr * 64 + ti * 32 + (r & 3) + 8 * (r >> 2) + 4 * kg;
                    Out[(size_t)row * D_MODEL + col] = (f16)((acc[ti][tj][r] + bc) * sc);
                }
        }
    } else {
        // V transposed: Vt[(b*16+h)*64 + d][s]
#pragma unroll
        for (int tj = 0; tj < 2; ++tj) {
            const int col = n0 + wc * 64 + tj * 32 + l31;
            const float bc = bias[col];
            const int h = col >> 6, d = col & 63;
#pragma unroll
            for (int ti = 0; ti < 2; ++ti)
#pragma unroll
                for (int r = 0; r < 16; ++r) {
                    const int row = m0 + wr * 64 + ti * 32 + (r & 3) + 8 * (r >> 2) + 4 * kg;
                    const int bb = row >> 11, s = row & (SEQ - 1);
                    Vt[(size_t)((bb * NHEADS + h) * DK + d) * SEQ + s] = (f16)(acc[ti][tj][r] + bc);
                }
        }
    }
}

// Output projection, split-K=2, XCD-swizzled grid (x=mtile 32, y=ntile 8, z).
__global__ __launch_bounds__(256, 3) void oproj_splitk(
    const f16* __restrict__ A, const f16* __restrict__ Wm,
    float* __restrict__ P0, float* __restrict__ P1)
{
    const int z = blockIdx.z;
    const int m0 = blockIdx.x * 128, n0 = blockIdx.y * 128;   // XCD swizzle
    f32x16 acc[2][2];
    gemm128_core(A, Wm, m0, n0, z * 512, z * 512 + 512, acc);

    float* Out = z == 0 ? P0 : P1;
    const int t = threadIdx.x, lane = t & 63, w = t >> 6;
    const int l31 = lane & 31, kg = lane >> 5;
    const int wr = w >> 1, wc = w & 1;
#pragma unroll
    for (int tj = 0; tj < 2; ++tj) {
        const int col = n0 + wc * 64 + tj * 32 + l31;
#pragma unroll
        for (int ti = 0; ti < 2; ++ti)
#pragma unroll
            for (int r = 0; r < 16; ++r) {
                const int row = m0 + wr * 64 + ti * 32 + (r & 3) + 8 * (r >> 2) + 4 * kg;
                Out[(size_t)row * D_MODEL + col] = acc[ti][tj][r];
            }
    }
}

// Reduce partials + bias -> final fp32 output.
__global__ __launch_bounds__(256) void reduce_bias(
    const float* __restrict__ P0, const float* __restrict__ P1,
    const float* __restrict__ bias, float* __restrict__ Out)
{
    const int n4 = MTOT * D_MODEL / 4;
    for (int i = blockIdx.x * 256 + threadIdx.x; i < n4; i += gridDim.x * 256) {
        float4 a = ((const float4*)P0)[i];
        float4 b = ((const float4*)P1)[i];
        float4 c = ((const float4*)bias)[i & 255];
        float4 o = {a.x + b.x + c.x, a.y + b.y + c.y,
                    a.z + b.z + c.z, a.w + b.w + c.w};
        ((float4*)Out)[i] = o;
    }
}

// ---------------------------------------------------------------------------
// Flash attention v8b = R11 structure (keys in thirds, 24.5 KB LDS, per-wave
// Ps reuse) with the launch bound FIXED: (256,4) not (256,6). R11's (256,6)
// forced VGPR 64->40 => accumulator spill storm (419 MB fetch / 523 MB write).
// At VGPR=64 HW allows 8 waves/SIMD, so 6 blocks/CU (147 KB LDS) fits
// naturally — residency is set by LDS/VGPR, not the hint.
// Grid (bh=32, qt=16, 3) = 1536 blocks; id%8 = bh%8 keeps K/V XCD locality.
// ---------------------------------------------------------------------------
__global__ __launch_bounds__(256, 4) void mha_mfma_v8(
    const f16* __restrict__ Qh, const f16* __restrict__ Kh,
    const f16* __restrict__ Vt, f16* __restrict__ Op, float* __restrict__ sp)
{
    __shared__ __align__(16) f16 Ks[4096];
    __shared__ __align__(16) f16 Vc[4096];
    __shared__ __align__(16) f16 Ps[64 * 68];

    const int t    = threadIdx.x;
    const int w    = t >> 6;
    const int lane = t & 63;
    const int quad = lane >> 4, l15 = lane & 15;

    const int bh = blockIdx.x, qt = blockIdx.y, third = blockIdx.z;
    const int b  = bh >> 4,    h  = bh & 15;
    const int q0 = qt * 128;

    f16x8 aQ[2][2];
#pragma unroll
    for (int s = 0; s < 2; ++s)
#pragma unroll
        for (int c = 0; c < 2; ++c)
            aQ[s][c] = *(const f16x8*)&Qh[
                (size_t)(b * SEQ + q0 + w * 32 + s * 16 + l15) * D_MODEL
                + h * DK + c * 32 + quad * 8];

    const f16* gK[2]; const f16* gV[2]; int ldst[2];
#pragma unroll
    for (int jj = 0; jj < 2; ++jj) {
        const int kc = w * 2 + jj;
        gK[jj] = Kh + (size_t)(b * SEQ + lane) * D_MODEL + h * DK + kc * 8;
        gV[jj] = Vt + (size_t)(bh * DK + lane) * SEQ + kc * 8;
        ldst[jj] = __builtin_amdgcn_readfirstlane(kc * 512);
    }
    auto* ldsK = (__attribute__((address_space(3))) f16*)Ks;
    auto* ldsV = (__attribute__((address_space(3))) f16*)Vc;

    const f16x8 onesB = {(f16)1.f, (f16)1.f, (f16)1.f, (f16)1.f,
                         (f16)1.f, (f16)1.f, (f16)1.f, (f16)1.f};

    f32x4 o[2][4];
#pragma unroll
    for (int s = 0; s < 2; ++s)
#pragma unroll
        for (int j = 0; j < 4; ++j) o[s][j] = (f32x4){0.f, 0.f, 0.f, 0.f};
    f32x4 sacc[2] = {(f32x4){0.f, 0.f, 0.f, 0.f}, (f32x4){0.f, 0.f, 0.f, 0.f}};

    const int kt0   = third * 11;                         // 0, 11, 22
    const int ktend = (third == 2) ? 32 : kt0 + 11;       // 11, 22, 32
    for (int kt = kt0; kt < ktend; ++kt) {
#pragma unroll
        for (int jj = 0; jj < 2; ++jj) {
            __builtin_amdgcn_global_load_lds(
                (const __attribute__((address_space(1))) void*)(gK[jj] + (size_t)kt * 64 * D_MODEL),
                (__attribute__((address_space(3))) void*)(ldsK + ldst[jj]), 16, 0, 0);
            __builtin_amdgcn_global_load_lds(
                (const __attribute__((address_space(1))) void*)(gV[jj] + kt * 64),
                (__attribute__((address_space(3))) void*)(ldsV + ldst[jj]), 16, 0, 0);
        }
        __syncthreads();

        f16x8 bK[4][2], bV[4][2];
#pragma unroll
        for (int f = 0; f < 4; ++f)
#pragma unroll
            for (int c = 0; c < 2; ++c) {
                const int slot = ((c * 4 + quad) * 64 + f * 16 + l15) * 8;
                bK[f][c] = *(const f16x8*)&Ks[slot];
                bV[f][c] = *(const f16x8*)&Vc[slot];
            }

#pragma unroll
        for (int s = 0; s < 2; ++s) {
            f32x4 sc[4];
#pragma unroll
            for (int f = 0; f < 4; ++f) {
                f32x4 a = (f32x4){0.f, 0.f, 0.f, 0.f};
                a = __builtin_amdgcn_mfma_f32_16x16x32_f16(aQ[s][0], bK[f][0], a, 0, 0, 0);
                a = __builtin_amdgcn_mfma_f32_16x16x32_f16(aQ[s][1], bK[f][1], a, 0, 0, 0);
                sc[f] = a;
            }

#pragma unroll
            for (int f = 0; f < 4; ++f)
#pragma unroll
                for (int r = 0; r < 4; ++r)
                    sc[f][r] = __builtin_exp2f(sc[f][r]);

            // per-wave 16-row Ps region, reused across s (in-order DS)
#pragma unroll
            for (int f = 0; f < 4; ++f)
#pragma unroll
                for (int r = 0; r < 4; ++r)
                    Ps[(w * 16 + quad * 4 + r) * 68 + f * 16 + l15] = (f16)sc[f][r];

            f16x8 aP[2];
#pragma unroll
            for (int c = 0; c < 2; ++c) {
                const int off = (w * 16 + l15) * 68 + c * 32 + quad * 8;
                f16x4 lo = *(const f16x4*)&Ps[off];
                f16x4 hi = *(const f16x4*)&Ps[off + 4];
                aP[c] = __builtin_shufflevector(lo, hi, 0, 1, 2, 3, 4, 5, 6, 7);
            }

#pragma unroll
            for (int j = 0; j < 4; ++j) {
                o[s][j] = __builtin_amdgcn_mfma_f32_16x16x32_f16(aP[0], bV[j][0], o[s][j], 0, 0, 0);
                o[s][j] = __builtin_amdgcn_mfma_f32_16x16x32_f16(aP[1], bV[j][1], o[s][j], 0, 0, 0);
            }
            sacc[s] = __builtin_amdgcn_mfma_f32_16x16x32_f16(aP[0], onesB, sacc[s], 0, 0, 0);
            sacc[s] = __builtin_amdgcn_mfma_f32_16x16x32_f16(aP[1], onesB, sacc[s], 0, 0, 0);
        }
        __syncthreads();
    }

    // ---- epilogue: unnormalized O partial (f16) + sacc partial (f32) ----
#pragma unroll
    for (int s = 0; s < 2; ++s)
#pragma unroll
        for (int r = 0; r < 4; ++r) {
            const int qrow = q0 + w * 32 + s * 16 + quad * 4 + r;
            const size_t base = ((size_t)(third * 32 + bh) * SEQ + qrow) * DK;
#pragma unroll
            for (int j = 0; j < 4; ++j)
                Op[base + j * 16 + l15] = (f16)o[s][j][r];
            if (l15 == 0)
                sp[(size_t)(third * 32 + bh) * SEQ + qrow] = sacc[s][r];
        }
}

// Combine: O = (O0+O1+O2)/(s0+s1+s2) -> ATh f16 natural [B*S, D_MODEL].
__global__ __launch_bounds__(256) void mha_combine(
    const f16* __restrict__ Op, const float* __restrict__ sp,
    f16* __restrict__ ATh)
{
    const int gid = blockIdx.x * 256 + threadIdx.x;
    const int d4 = gid & 15;
    const int q  = (gid >> 4) & (SEQ - 1);
    const int bh = gid >> 15;
    const int b = bh >> 4, h = bh & 15;

    float acc[4] = {0.f, 0.f, 0.f, 0.f};
    float ssum = 0.f;
#pragma unroll
    for (int tpart = 0; tpart < 3; ++tpart) {
        const size_t idx = ((size_t)(tpart * 32 + bh) * SEQ + q) * DK + d4 * 4;
        f16x4 a = *(const f16x4*)&Op[idx];
#pragma unroll
        for (int m = 0; m < 4; ++m) acc[m] += (float)a[m];
        ssum += sp[(size_t)(tpart * 32 + bh) * SEQ + q];
    }
    const float inv = 1.f / ssum;
    f16x4 r;
#pragma unroll
    for (int m = 0; m < 4; ++m) r[m] = (f16)(acc[m] * inv);
    *(f16x4*)&ATh[((size_t)(b * SEQ + q)) * D_MODEL + h * DK + d4 * 4] = r;
}

// ---------------------------------------------------------------------------
extern "C" void kernel_launch(void* const* d_in, const int* in_sizes, int n_in,
                              void* d_out, int out_size, void* d_ws, size_t ws_size,
                              hipStream_t stream)
{
    const float* query = (const float*)d_in[0];
    const float* key   = (const float*)d_in[1];
    const float* value = (const float*)d_in[2];
    const float* Wq    = (const float*)d_in[3];
    const float* bq    = (const float*)d_in[4];
    const float* Wk    = (const float*)d_in[5];
    const float* bk    = (const float*)d_in[6];
    const float* Wv    = (const float*)d_in[7];
    const float* bv    = (const float*)d_in[8];
    const float* Wo    = (const float*)d_in[9];
    const float* bo    = (const float*)d_in[10];
    float* out = (float*)d_out;

    // ws layout (f16 elems), 64 MB total:
    //   Qf Kf Vf (4M ea) | Wqh Wkh Wvh Woh (1M ea) | Qh Kh Vt ATh (4M ea)
    // Stream-ordered overlays of dead regions:
    //   Op (12M f16 = 24 MB, 3 thirds) over Qf+Kf+Vf (dead after qkv_gemm)
    //   sp (192K f32) over Wqh (dead after qkv_gemm)
    //   P0 (4M f32) over Qf+Kf (Op dead after combine)
    //   P1 (4M f32) over Qh+Kh (dead after combine)
    f16* Qf  = (f16*)d_ws;
    f16* Kf  = Qf  + (size_t)MTOT * D_MODEL;
    f16* Vf  = Kf  + (size_t)MTOT * D_MODEL;
    f16* Wqh = Vf  + (size_t)MTOT * D_MODEL;
    f16* Wkh = Wqh + (size_t)D_MODEL * D_MODEL;
    f16* Wvh = Wkh + (size_t)D_MODEL * D_MODEL;
    f16* Woh = Wvh + (size_t)D_MODEL * D_MODEL;
    f16* Qh  = Woh + (size_t)D_MODEL * D_MODEL;
    f16* Kh  = Qh  + (size_t)MTOT * D_MODEL;
    f16* Vt  = Kh  + (size_t)MTOT * D_MODEL;
    f16* ATh = Vt  + (size_t)MTOT * D_MODEL;

    f16*   Op = Qf;                 // 3*32*2048*64 f16 = 12M f16 = 24 MB
    float* sp = (float*)Wqh;        // 3*32*2048 f32 = 0.75 MB
    float* P0 = (float*)Qf;
    float* P1 = (float*)Qh;

    cvt_f32_to_f16<<<dim3(1024, 7), 256, 0, stream>>>(
        query, key, value, Wq, Wk, Wv, Wo, Qf, Kf, Vf, Wqh, Wkh, Wvh, Woh);

    qkv_gemm<<<dim3(MTOT / 128, D_MODEL / 128, 3), 256, 0, stream>>>(
        Qf, Kf, Vf, Wqh, Wkh, Wvh, bq, bk, bv, Qh, Kh, Vt);

    mha_mfma_v8<<<dim3(NBATCH * NHEADS, SEQ / 128, 3), 256, 0, stream>>>(
        Qh, Kh, Vt, Op, sp);

    mha_combine<<<dim3(MTOT * D_MODEL / 4 / 256), 256, 0, stream>>>(Op, sp, ATh);

    oproj_splitk<<<dim3(MTOT / 128, D_MODEL / 128, 2), 256, 0, stream>>>(ATh, Woh, P0, P1);

    reduce_bias<<<dim3(1024), 256, 0, stream>>>(P0, P1, bo, out);
}